// Round 3
// baseline (1276.457 us; speedup 1.0000x reference)
//
#include <hip/hip_runtime.h>

#define Bsz 1024
#define Tt  256
#define Vv  32004
#define Dd  50
#define Hh  64
#define RR  32   // vocab rows per build_tables block
#define CC  8    // rows per accumulator chunk (16 live accs -> no spill)

// ---------------------------------------------------------------------------
// Prologue: tab[v][g] = sum_d emb[v][d] * Wih[g][d] + bih[g] + bhh[g]
// 32 vocab rows per block, emb tile in LDS, processed in 4 chunks of 8 rows
// so only 16 accumulators are live (round-2 version kept 64 -> scratch spill,
// 1.8 GB of HBM scratch traffic). Weights re-streamed per chunk (L1-resident).
// ---------------------------------------------------------------------------
__launch_bounds__(256, 4)
__global__ void build_tables(const float* __restrict__ emb,
                             const float* __restrict__ Wih1,
                             const float* __restrict__ bih1,
                             const float* __restrict__ bhh1,
                             const float* __restrict__ Wih2,
                             const float* __restrict__ bih2,
                             const float* __restrict__ bhh2,
                             float* __restrict__ tab1,
                             float* __restrict__ tab2) {
    const int v0 = blockIdx.x * RR;
    const int g  = threadIdx.x;          // 0..255
    const int nr = min(RR, Vv - v0);     // rows in this block (tail: 4)

    __shared__ float elds[RR * Dd];      // 32 x 50 = 6.4 KB

    // coalesced flat copy of the emb tile (rows are contiguous)
    const int tile_elems = nr * Dd;
    for (int i = threadIdx.x; i < tile_elems; i += 256)
        elds[i] = emb[(size_t)v0 * Dd + i];
    __syncthreads();

    const float* w1 = Wih1 + (size_t)g * Dd;
    const float* w2 = Wih2 + (size_t)g * Dd;
    const float bias1 = bih1[g] + bhh1[g];
    const float bias2 = bih2[g] + bhh2[g];

    for (int c = 0; c < RR / CC; ++c) {              // 4 chunks of 8 rows
        float acc1[CC], acc2[CC];
#pragma unroll
        for (int r = 0; r < CC; ++r) { acc1[r] = 0.0f; acc2[r] = 0.0f; }

#pragma unroll
        for (int j = 0; j < Dd / 2; ++j) {           // 25 iters, float2 loads
            const float2 a = *(const float2*)(w1 + 2 * j);   // L1-hit after c=0
            const float2 b = *(const float2*)(w2 + 2 * j);
#pragma unroll
            for (int r = 0; r < CC; ++r) {
                // broadcast LDS read (same addr across wave): float2
                const float2 e = *(const float2*)(&elds[(c * CC + r) * Dd + 2 * j]);
                acc1[r] += e.x * a.x + e.y * a.y;
                acc2[r] += e.x * b.x + e.y * b.y;
            }
        }

#pragma unroll
        for (int r = 0; r < CC; ++r) {
            const int row = c * CC + r;
            if (row < nr) {
                tab1[(size_t)(v0 + row) * 256 + g] = acc1[r] + bias1;
                tab2[(size_t)(v0 + row) * 256 + g] = acc2[r] + bias2;
            }
        }
    }
}

// ---------------------------------------------------------------------------
// Main recurrence. One block (256 threads) per batch row b.
// wave w = gate type (i,f,g,o), lane l = hidden unit. gate index = tid.
// Whh row cached in 64 VGPRs per lane; h exchanged via per-wave LDS buffer;
// activated gates exchanged via double-buffered LDS, 1 barrier per step.
// ---------------------------------------------------------------------------
__launch_bounds__(256, 4)
__global__ void lstm_main(const int*   __restrict__ s1,
                          const int*   __restrict__ s2,
                          const int*   __restrict__ len1,
                          const int*   __restrict__ len2,
                          const float* __restrict__ tab1,
                          const float* __restrict__ tab2,
                          const float* __restrict__ Whh1,
                          const float* __restrict__ Whh2,
                          const float* __restrict__ Wl1,
                          const float* __restrict__ bl1,
                          const float* __restrict__ Wl2,
                          const float* __restrict__ bl2,
                          float* __restrict__ out) {
    const int b   = blockIdx.x;
    const int tid = threadIdx.x;
    const int w   = tid >> 6;            // wave id = gate type
    const int l   = tid & 63;            // hidden unit
    const int gi  = tid;                 // gate index = 64*w + l

    __shared__ __align__(16) float hbuf[4][2][Hh];  // per-wave h, double buffered
    __shared__ float gbuf[2][256];                  // activated gates, double buffered
    __shared__ __align__(16) float h2s[Hh];
    __shared__ float ys[128];

    // activation constants: waves 0,1,3 -> sigmoid; wave 2 -> tanh = 2*sig(2x)-1
    const float m  = (w == 2) ? 2.0f : 1.0f;
    const float Am = (w == 2) ? 2.0f : 1.0f;
    const float Bc = (w == 2) ? -1.0f : 0.0f;

    float wreg[64];
    float c = 0.0f, h_init = 0.0f;

    for (int phase = 0; phase < 2; ++phase) {
        const int*   sent = phase ? (s2 + (size_t)b * Tt) : (s1 + (size_t)b * Tt);
        const float* tab  = phase ? tab2 : tab1;
        const float* Whh  = phase ? Whh2 : Whh1;
        const int*   lenp = phase ? (len2 + (size_t)b * Hh) : (len1 + (size_t)b * Hh);

        // cache my Whh row (64 floats) in registers
        const float* wp = Whh + (size_t)gi * Hh;
#pragma unroll
        for (int j = 0; j < 16; ++j) {
            const float4 t4 = *(const float4*)(wp + 4 * j);
            wreg[4 * j + 0] = t4.x;
            wreg[4 * j + 1] = t4.y;
            wreg[4 * j + 2] = t4.z;
            wreg[4 * j + 3] = t4.w;
        }
        const int myidx = lenp[l];

        hbuf[w][0][l] = h_init;          // wave-local init
        float selh = 0.0f, selc = 0.0f;

        // token / table-row software pipeline (2 steps ahead)
        const int t0 = sent[0];
        const int t1 = sent[1];
        int tok_nn   = sent[2];
        float xw_cur = tab[(size_t)t0 * 256 + gi];
        float xw_nxt = tab[(size_t)t1 * 256 + gi];

        auto step = [&](int t, int rb, int wb2) {
            // issue future loads: xw for t+2, token for t+3
            const float xw_fut = tab[(size_t)tok_nn * 256 + gi];
            const int   nidx   = (t + 3 < Tt) ? (t + 3) : (Tt - 1);
            const int   tok_fut = sent[nidx];

            // GEMV: gate = xw + sum_k h[k] * Whh[gi][k]
            const float4* h4 = (const float4*)hbuf[w][rb];
            float a0 = xw_cur, a1 = 0.0f, a2 = 0.0f, a3 = 0.0f;
#pragma unroll
            for (int kk = 0; kk < 16; ++kk) {
                const float4 hv = h4[kk];   // broadcast read
                a0 += hv.x * wreg[4 * kk + 0];
                a1 += hv.y * wreg[4 * kk + 1];
                a2 += hv.z * wreg[4 * kk + 2];
                a3 += hv.w * wreg[4 * kk + 3];
            }
            const float acc = (a0 + a1) + (a2 + a3);

            // activation (branch-free sigmoid/tanh select per wave)
            const float sg  = 1.0f / (1.0f + __expf(-m * acc));
            gbuf[rb][gi] = Am * sg + Bc;
            __syncthreads();

            // redundant c/h update in every wave (no second barrier needed)
            const float iv = gbuf[rb][l];
            const float fv = gbuf[rb][64 + l];
            const float gv = gbuf[rb][128 + l];
            const float ov = gbuf[rb][192 + l];
            c = fv * c + iv * gv;
            const float th = 2.0f / (1.0f + __expf(-2.0f * c)) - 1.0f;
            const float h  = ov * th;

            const bool hit = (t == myidx);
            selh = hit ? h : selh;
            selc = hit ? c : selc;

            hbuf[w][wb2][l] = h;            // wave-local write for next step

            // rotate pipeline
            xw_cur = xw_nxt;
            xw_nxt = xw_fut;
            tok_nn = tok_fut;
        };

        for (int t = 0; t < Tt; t += 2) {
            step(t,     0, 1);
            step(t + 1, 1, 0);
        }

        c = selc;        // LSTM2 init / final gathered state
        h_init = selh;
    }

    // ---------------- epilogue MLP: tanh(h2 @ Wl1.T + bl1) @ Wl2.T + bl2 ----
    if (w == 0) h2s[l] = h_init;
    __syncthreads();
    if (tid < 128) {
        float acc = bl1[tid];
        const float* wl = Wl1 + (size_t)tid * 64;
#pragma unroll
        for (int k = 0; k < 64; ++k) acc += h2s[k] * wl[k];
        const float sg = 1.0f / (1.0f + __expf(-2.0f * acc));
        ys[tid] = 2.0f * sg - 1.0f;
    }
    __syncthreads();
    if (tid < 4) {
        float acc = bl2[tid];
        const float* wl = Wl2 + (size_t)tid * 128;
#pragma unroll
        for (int k = 0; k < 128; ++k) acc += ys[k] * wl[k];
        out[(size_t)b * 4 + tid] = acc;
    }
}

// ---------------------------------------------------------------------------
extern "C" void kernel_launch(void* const* d_in, const int* in_sizes, int n_in,
                              void* d_out, int out_size, void* d_ws, size_t ws_size,
                              hipStream_t stream) {
    const int*   s1   = (const int*)d_in[0];
    const int*   s2   = (const int*)d_in[1];
    const int*   l1   = (const int*)d_in[2];
    const int*   l2   = (const int*)d_in[3];
    // d_in[4], d_in[5] (s1_s, s2_s) unused by the reference
    const float* emb  = (const float*)d_in[6];
    const float* Wih1 = (const float*)d_in[7];
    const float* Whh1 = (const float*)d_in[8];
    const float* bih1 = (const float*)d_in[9];
    const float* bhh1 = (const float*)d_in[10];
    const float* Wih2 = (const float*)d_in[11];
    const float* Whh2 = (const float*)d_in[12];
    const float* bih2 = (const float*)d_in[13];
    const float* bhh2 = (const float*)d_in[14];
    const float* Wl1  = (const float*)d_in[15];
    const float* bl1  = (const float*)d_in[16];
    const float* Wl2  = (const float*)d_in[17];
    const float* bl2  = (const float*)d_in[18];
    float* out = (float*)d_out;

    float* tab1 = (float*)d_ws;                       // [V,256] fp32
    float* tab2 = tab1 + (size_t)Vv * 256;            // [V,256] fp32  (total 65.6 MB)

    build_tables<<<(Vv + RR - 1) / RR, 256, 0, stream>>>(emb, Wih1, bih1, bhh1,
                                                         Wih2, bih2, bhh2, tab1, tab2);
    lstm_main<<<Bsz, 256, 0, stream>>>(s1, s2, l1, l2, tab1, tab2,
                                       Whh1, Whh2, Wl1, bl1, Wl2, bl2, out);
}

// Round 4
// 608.957 us; speedup vs baseline: 2.0961x; 2.0961x over previous
//
#include <hip/hip_runtime.h>

#define Bsz 1024
#define Tt  256
#define Vv  32004
#define Dd  50
#define Hh  64
#define RR  32   // vocab rows per build_tables block

// ---------------------------------------------------------------------------
// Prologue: tab[v][g] = sum_d emb[v][d] * Wih[g][d] + bih[g] + bhh[g]
// One table per block (blockIdx.y), 32 vocab rows per block (blockIdx.x).
// Both operands staged in LDS:
//   wpack[13][256] float4 : gate-major, d packed in 4s, last slot zero-padded
//   elds [32][52]  float  : emb tile, rows padded to 52 (16B-aligned, pad=0)
// Registers carry only 8 accumulators + 1 float4 of each operand (~30 VGPRs)
// -> nothing for LICM to hoist, no scratch spill (rounds 2-3 failure mode).
// ---------------------------------------------------------------------------
__launch_bounds__(256)
__global__ void build_tables(const float* __restrict__ emb,
                             const float* __restrict__ Wih1,
                             const float* __restrict__ bih1,
                             const float* __restrict__ bhh1,
                             const float* __restrict__ Wih2,
                             const float* __restrict__ bih2,
                             const float* __restrict__ bhh2,
                             float* __restrict__ tab1,
                             float* __restrict__ tab2) {
    const int v0 = blockIdx.x * RR;
    const int g  = threadIdx.x;              // gate 0..255
    const int nr = min(RR, Vv - v0);         // rows in this block (tail: 4)

    const float* Wih = blockIdx.y ? Wih2 : Wih1;
    const float* bih = blockIdx.y ? bih2 : bih1;
    const float* bhh = blockIdx.y ? bhh2 : bhh1;
    float*       tab = blockIdx.y ? tab2 : tab1;

    __shared__ __align__(16) float4 wpack[13 * 256];  // 53.2 KB
    __shared__ __align__(16) float  elds[RR * 52];    // 6.66 KB  (59.9 KB total)

    // ---- stage weights: thread g repacks its gate row (50 floats, 8B-aligned)
    {
        const float* wrow = Wih + (size_t)g * Dd;
#pragma unroll
        for (int j = 0; j < 12; ++j) {
            const float2 a = *(const float2*)(wrow + 4 * j);
            const float2 b = *(const float2*)(wrow + 4 * j + 2);
            wpack[j * 256 + g] = make_float4(a.x, a.y, b.x, b.y);
        }
        const float2 t = *(const float2*)(wrow + 48);
        wpack[12 * 256 + g] = make_float4(t.x, t.y, 0.0f, 0.0f);
    }

    // ---- stage emb tile with zero-padded cols 50..51
    for (int i = threadIdx.x; i < nr * 52; i += 256) {
        const int row = i / 52;
        const int col = i - row * 52;
        elds[i] = (col < Dd) ? emb[(size_t)(v0 + row) * Dd + col] : 0.0f;
    }
    __syncthreads();

    const float bias = bih[g] + bhh[g];

    for (int c = 0; c < RR / 8; ++c) {        // 4 chunks of 8 rows
        const int r0 = c * 8;
        float acc[8];
#pragma unroll
        for (int r = 0; r < 8; ++r) acc[r] = 0.0f;

#pragma unroll
        for (int j = 0; j < 13; ++j) {
            const float4 w = wpack[j * 256 + g];          // lanes contiguous
#pragma unroll
            for (int r = 0; r < 8; ++r) {                  // broadcast reads
                const float4 e = *(const float4*)(&elds[(r0 + r) * 52 + 4 * j]);
                acc[r] += e.x * w.x + e.y * w.y + e.z * w.z + e.w * w.w;
            }
        }

#pragma unroll
        for (int r = 0; r < 8; ++r) {
            const int row = r0 + r;
            if (row < nr)
                tab[(size_t)(v0 + row) * 256 + g] = acc[r] + bias;
        }
    }
}

// ---------------------------------------------------------------------------
// Main recurrence. One block (256 threads) per batch row b.
// wave w = gate type (i,f,g,o), lane l = hidden unit. gate index = tid.
// Whh row cached in 64 VGPRs per lane; h exchanged via per-wave LDS buffer;
// activated gates exchanged via double-buffered LDS, 1 barrier per step.
// ---------------------------------------------------------------------------
__launch_bounds__(256, 4)
__global__ void lstm_main(const int*   __restrict__ s1,
                          const int*   __restrict__ s2,
                          const int*   __restrict__ len1,
                          const int*   __restrict__ len2,
                          const float* __restrict__ tab1,
                          const float* __restrict__ tab2,
                          const float* __restrict__ Whh1,
                          const float* __restrict__ Whh2,
                          const float* __restrict__ Wl1,
                          const float* __restrict__ bl1,
                          const float* __restrict__ Wl2,
                          const float* __restrict__ bl2,
                          float* __restrict__ out) {
    const int b   = blockIdx.x;
    const int tid = threadIdx.x;
    const int w   = tid >> 6;            // wave id = gate type
    const int l   = tid & 63;            // hidden unit
    const int gi  = tid;                 // gate index = 64*w + l

    __shared__ __align__(16) float hbuf[4][2][Hh];  // per-wave h, double buffered
    __shared__ float gbuf[2][256];                  // activated gates, double buffered
    __shared__ __align__(16) float h2s[Hh];
    __shared__ float ys[128];

    // activation constants: waves 0,1,3 -> sigmoid; wave 2 -> tanh = 2*sig(2x)-1
    const float m  = (w == 2) ? 2.0f : 1.0f;
    const float Am = (w == 2) ? 2.0f : 1.0f;
    const float Bc = (w == 2) ? -1.0f : 0.0f;

    float wreg[64];
    float c = 0.0f, h_init = 0.0f;

    for (int phase = 0; phase < 2; ++phase) {
        const int*   sent = phase ? (s2 + (size_t)b * Tt) : (s1 + (size_t)b * Tt);
        const float* tab  = phase ? tab2 : tab1;
        const float* Whh  = phase ? Whh2 : Whh1;
        const int*   lenp = phase ? (len2 + (size_t)b * Hh) : (len1 + (size_t)b * Hh);

        // cache my Whh row (64 floats) in registers
        const float* wp = Whh + (size_t)gi * Hh;
#pragma unroll
        for (int j = 0; j < 16; ++j) {
            const float4 t4 = *(const float4*)(wp + 4 * j);
            wreg[4 * j + 0] = t4.x;
            wreg[4 * j + 1] = t4.y;
            wreg[4 * j + 2] = t4.z;
            wreg[4 * j + 3] = t4.w;
        }
        const int myidx = lenp[l];

        hbuf[w][0][l] = h_init;          // wave-local init
        float selh = 0.0f, selc = 0.0f;

        // token / table-row software pipeline (2 steps ahead)
        const int t0 = sent[0];
        const int t1 = sent[1];
        int tok_nn   = sent[2];
        float xw_cur = tab[(size_t)t0 * 256 + gi];
        float xw_nxt = tab[(size_t)t1 * 256 + gi];

        auto step = [&](int t, int rb, int wb2) {
            // issue future loads: xw for t+2, token for t+3
            const float xw_fut = tab[(size_t)tok_nn * 256 + gi];
            const int   nidx   = (t + 3 < Tt) ? (t + 3) : (Tt - 1);
            const int   tok_fut = sent[nidx];

            // GEMV: gate = xw + sum_k h[k] * Whh[gi][k]
            const float4* h4 = (const float4*)hbuf[w][rb];
            float a0 = xw_cur, a1 = 0.0f, a2 = 0.0f, a3 = 0.0f;
#pragma unroll
            for (int kk = 0; kk < 16; ++kk) {
                const float4 hv = h4[kk];   // broadcast read
                a0 += hv.x * wreg[4 * kk + 0];
                a1 += hv.y * wreg[4 * kk + 1];
                a2 += hv.z * wreg[4 * kk + 2];
                a3 += hv.w * wreg[4 * kk + 3];
            }
            const float acc = (a0 + a1) + (a2 + a3);

            // activation (branch-free sigmoid/tanh select per wave)
            const float sg  = 1.0f / (1.0f + __expf(-m * acc));
            gbuf[rb][gi] = Am * sg + Bc;
            __syncthreads();

            // redundant c/h update in every wave (no second barrier needed)
            const float iv = gbuf[rb][l];
            const float fv = gbuf[rb][64 + l];
            const float gv = gbuf[rb][128 + l];
            const float ov = gbuf[rb][192 + l];
            c = fv * c + iv * gv;
            const float th = 2.0f / (1.0f + __expf(-2.0f * c)) - 1.0f;
            const float h  = ov * th;

            const bool hit = (t == myidx);
            selh = hit ? h : selh;
            selc = hit ? c : selc;

            hbuf[w][wb2][l] = h;            // wave-local write for next step

            // rotate pipeline
            xw_cur = xw_nxt;
            xw_nxt = xw_fut;
            tok_nn = tok_fut;
        };

        for (int t = 0; t < Tt; t += 2) {
            step(t,     0, 1);
            step(t + 1, 1, 0);
        }

        c = selc;        // LSTM2 init / final gathered state
        h_init = selh;
    }

    // ---------------- epilogue MLP: tanh(h2 @ Wl1.T + bl1) @ Wl2.T + bl2 ----
    if (w == 0) h2s[l] = h_init;
    __syncthreads();
    if (tid < 128) {
        float acc = bl1[tid];
        const float* wl = Wl1 + (size_t)tid * 64;
#pragma unroll
        for (int k = 0; k < 64; ++k) acc += h2s[k] * wl[k];
        const float sg = 1.0f / (1.0f + __expf(-2.0f * acc));
        ys[tid] = 2.0f * sg - 1.0f;
    }
    __syncthreads();
    if (tid < 4) {
        float acc = bl2[tid];
        const float* wl = Wl2 + (size_t)tid * 128;
#pragma unroll
        for (int k = 0; k < 128; ++k) acc += ys[k] * wl[k];
        out[(size_t)b * 4 + tid] = acc;
    }
}

// ---------------------------------------------------------------------------
extern "C" void kernel_launch(void* const* d_in, const int* in_sizes, int n_in,
                              void* d_out, int out_size, void* d_ws, size_t ws_size,
                              hipStream_t stream) {
    const int*   s1   = (const int*)d_in[0];
    const int*   s2   = (const int*)d_in[1];
    const int*   l1   = (const int*)d_in[2];
    const int*   l2   = (const int*)d_in[3];
    // d_in[4], d_in[5] (s1_s, s2_s) unused by the reference
    const float* emb  = (const float*)d_in[6];
    const float* Wih1 = (const float*)d_in[7];
    const float* Whh1 = (const float*)d_in[8];
    const float* bih1 = (const float*)d_in[9];
    const float* bhh1 = (const float*)d_in[10];
    const float* Wih2 = (const float*)d_in[11];
    const float* Whh2 = (const float*)d_in[12];
    const float* bih2 = (const float*)d_in[13];
    const float* bhh2 = (const float*)d_in[14];
    const float* Wl1  = (const float*)d_in[15];
    const float* bl1  = (const float*)d_in[16];
    const float* Wl2  = (const float*)d_in[17];
    const float* bl2  = (const float*)d_in[18];
    float* out = (float*)d_out;

    float* tab1 = (float*)d_ws;                       // [V,256] fp32
    float* tab2 = tab1 + (size_t)Vv * 256;            // [V,256] fp32  (total 65.6 MB)

    dim3 grid((Vv + RR - 1) / RR, 2);
    build_tables<<<grid, 256, 0, stream>>>(emb, Wih1, bih1, bhh1,
                                           Wih2, bih2, bhh2, tab1, tab2);
    lstm_main<<<Bsz, 256, 0, stream>>>(s1, s2, l1, l2, tab1, tab2,
                                       Whh1, Whh2, Wl1, bl1, Wl2, bl2, out);
}

// Round 5
// 459.180 us; speedup vs baseline: 2.7799x; 1.3262x over previous
//
#include <hip/hip_runtime.h>

#define Bsz 1024
#define Tt  256
#define Vv  32004
#define Dd  50
#define Hh  64
#define RR  32   // vocab rows per build_tables block

typedef __bf16 b16x8 __attribute__((ext_vector_type(8)));
typedef float  f32x4 __attribute__((ext_vector_type(4)));

// barrier WITHOUT vmcnt(0) drain: LDS ordering only, in-flight global loads
// (the xw register prefetch) survive across it. __syncthreads would drain
// vmcnt(0) and kill the 2-step prefetch distance.
__device__ __forceinline__ void barrier_novm() {
    asm volatile("s_waitcnt lgkmcnt(0)\n\ts_barrier" ::: "memory");
}
__device__ __forceinline__ float fsig(float x) {
    return __fdividef(1.0f, 1.0f + __expf(-x));
}
__device__ __forceinline__ float ftanh(float x) {
    return 2.0f * __fdividef(1.0f, 1.0f + __expf(-2.0f * x)) - 1.0f;
}

// ---------------------------------------------------------------------------
// Prologue: tab[v][g] = sum_d emb[v][d] * Wih[g][d] + bih[g] + bhh[g]
// (unchanged from round 4 — verified no-spill, ~L2-resident weights)
// ---------------------------------------------------------------------------
__launch_bounds__(256)
__global__ void build_tables(const float* __restrict__ emb,
                             const float* __restrict__ Wih1,
                             const float* __restrict__ bih1,
                             const float* __restrict__ bhh1,
                             const float* __restrict__ Wih2,
                             const float* __restrict__ bih2,
                             const float* __restrict__ bhh2,
                             float* __restrict__ tab1,
                             float* __restrict__ tab2) {
    const int v0 = blockIdx.x * RR;
    const int g  = threadIdx.x;
    const int nr = min(RR, Vv - v0);

    const float* Wih = blockIdx.y ? Wih2 : Wih1;
    const float* bih = blockIdx.y ? bih2 : bih1;
    const float* bhh = blockIdx.y ? bhh2 : bhh1;
    float*       tab = blockIdx.y ? tab2 : tab1;

    __shared__ __align__(16) float4 wpack[13 * 256];
    __shared__ __align__(16) float  elds[RR * 52];

    {
        const float* wrow = Wih + (size_t)g * Dd;
#pragma unroll
        for (int j = 0; j < 12; ++j) {
            const float2 a = *(const float2*)(wrow + 4 * j);
            const float2 b = *(const float2*)(wrow + 4 * j + 2);
            wpack[j * 256 + g] = make_float4(a.x, a.y, b.x, b.y);
        }
        const float2 t = *(const float2*)(wrow + 48);
        wpack[12 * 256 + g] = make_float4(t.x, t.y, 0.0f, 0.0f);
    }
    for (int i = threadIdx.x; i < nr * 52; i += 256) {
        const int row = i / 52;
        const int col = i - row * 52;
        elds[i] = (col < Dd) ? emb[(size_t)(v0 + row) * Dd + col] : 0.0f;
    }
    __syncthreads();

    const float bias = bih[g] + bhh[g];

    for (int c = 0; c < RR / 8; ++c) {
        const int r0 = c * 8;
        float acc[8];
#pragma unroll
        for (int r = 0; r < 8; ++r) acc[r] = 0.0f;
#pragma unroll
        for (int j = 0; j < 13; ++j) {
            const float4 w = wpack[j * 256 + g];
#pragma unroll
            for (int r = 0; r < 8; ++r) {
                const float4 e = *(const float4*)(&elds[(r0 + r) * 52 + 4 * j]);
                acc[r] += e.x * w.x + e.y * w.y + e.z * w.z + e.w * w.w;
            }
        }
#pragma unroll
        for (int r = 0; r < 8; ++r) {
            const int row = r0 + r;
            if (row < nr)
                tab[(size_t)(v0 + row) * 256 + g] = acc[r] + bias;
        }
    }
}

// ---------------------------------------------------------------------------
// MFMA-batched recurrence: 256 blocks x 4 batch rows, 256 threads (4 waves).
// Per step: gates[256x4] = Whh(bf16)[256x64] @ h(bf16)[64x4] via 8 MFMAs/wave
// (16x16x32, A = Whh frags in VGPRs, B = h frags from LDS). Raw C -> LDS,
// then 1 update element per thread (fp32, exact xw from token table),
// h written back as bf16 for the next step's B-frags. 2 novm-barriers/step.
// ---------------------------------------------------------------------------
__launch_bounds__(256, 1)
__global__ void lstm_main(const int*   __restrict__ s1,
                          const int*   __restrict__ s2,
                          const int*   __restrict__ len1,
                          const int*   __restrict__ len2,
                          const float* __restrict__ tab1,
                          const float* __restrict__ tab2,
                          const float* __restrict__ Whh1,
                          const float* __restrict__ Whh2,
                          const float* __restrict__ Wl1,
                          const float* __restrict__ bl1,
                          const float* __restrict__ Wl2,
                          const float* __restrict__ bl2,
                          float* __restrict__ out) {
    const int tid  = threadIdx.x;
    const int w    = tid >> 6;        // wave id == update row r
    const int lane = tid & 63;        // update hidden unit j
    const int q    = lane >> 4;       // MFMA quad
    const int mn   = lane & 15;       // MFMA m (A) / n (B,C) index
    const int b0   = blockIdx.x * 4;  // 4 batch rows per block

    __shared__ __bf16 hsh[16][72];    // h (bf16), rows 4..15 stay zero; pad->2-way banks
    __shared__ float  graw[4][264];   // raw MFMA gates [row][gate], padded
    __shared__ int    toklds[4][256]; // this block's tokens for the phase
    __shared__ float  h2s[4][64];
    __shared__ float  ys[4][128];

    for (int i = tid; i < 16 * 72; i += 256) ((__bf16*)hsh)[i] = (__bf16)0.0f;

    float c = 0.0f, hval = 0.0f, selh = 0.0f, selc = 0.0f;
    const f32x4 zero4 = {0.0f, 0.0f, 0.0f, 0.0f};

    for (int phase = 0; phase < 2; ++phase) {
        const float* tab  = phase ? tab2 : tab1;
        const float* Whh  = phase ? Whh2 : Whh1;
        const int*   sent = phase ? s2 : s1;
        const int*   lenp = phase ? len2 : len1;

        // stage tokens: wave w stages batch row w
#pragma unroll
        for (int ii = 0; ii < 4; ++ii)
            toklds[w][lane + 64 * ii] = sent[(size_t)(b0 + w) * Tt + lane + 64 * ii];

        // A fragments: wave w owns gates 64w..64w+63 (4 tiles x 2 K-halves)
        // A[m = lane&15][k = quad*8 + j], fp32 -> bf16 (RNE) once per phase.
        b16x8 af[8];
#pragma unroll
        for (int i = 0; i < 4; ++i) {
            const int gate = 64 * w + 16 * i + mn;
#pragma unroll
            for (int kh = 0; kh < 2; ++kh) {
                const float* ar = Whh + (size_t)gate * Hh + kh * 32 + q * 8;
                const float4 f0 = *(const float4*)ar;
                const float4 f1 = *(const float4*)(ar + 4);
                b16x8 a;
                a[0] = (__bf16)f0.x; a[1] = (__bf16)f0.y;
                a[2] = (__bf16)f0.z; a[3] = (__bf16)f0.w;
                a[4] = (__bf16)f1.x; a[5] = (__bf16)f1.y;
                a[6] = (__bf16)f1.z; a[7] = (__bf16)f1.w;
                af[2 * i + kh] = a;
            }
        }

        const int myidx = lenp[(size_t)(b0 + w) * Hh + lane];

        if (phase) { c = selc; hval = selh; }   // gathered state seeds LSTM2
        hsh[w][lane] = (__bf16)hval;
        selh = 0.0f; selc = 0.0f;
        __syncthreads();

        // xw register prefetch, distance 2: slot A = even t, slot B = odd t
        const float* tabj = tab + lane;
        float4 Sa, Sb;
        {
            const int tk0 = toklds[w][0];
            Sa.x = tabj[tk0 * 256];       Sa.y = tabj[tk0 * 256 + 64];
            Sa.z = tabj[tk0 * 256 + 128]; Sa.w = tabj[tk0 * 256 + 192];
            const int tk1 = toklds[w][1];
            Sb.x = tabj[tk1 * 256];       Sb.y = tabj[tk1 * 256 + 64];
            Sb.z = tabj[tk1 * 256 + 128]; Sb.w = tabj[tk1 * 256 + 192];
        }

        auto step = [&](int t, float4& S) {
            // B frags: B[k = quad*8+j][n = lane&15] from hsh[n][k]
            const b16x8 bf0 = *(const b16x8*)&hsh[mn][q * 8];
            const b16x8 bf1 = *(const b16x8*)&hsh[mn][32 + q * 8];
#pragma unroll
            for (int i = 0; i < 4; ++i) {
                f32x4 acc = __builtin_amdgcn_mfma_f32_16x16x32_bf16(af[2 * i],     bf0, zero4, 0, 0, 0);
                acc       = __builtin_amdgcn_mfma_f32_16x16x32_bf16(af[2 * i + 1], bf1, acc,   0, 0, 0);
                if (mn < 4)   // C: row m = 4q+reg -> gate, col n = mn -> batch row
                    *(f32x4*)&graw[mn][64 * w + 16 * i + 4 * q] = acc;
            }
            barrier_novm();

            // update: thread owns (row w, hidden lane)
            const float gI = graw[w][lane]       + S.x;
            const float gF = graw[w][64 + lane]  + S.y;
            const float gG = graw[w][128 + lane] + S.z;
            const float gO = graw[w][192 + lane] + S.w;
            // refill S for t+2 (anti-dependency keeps issue after the reads above)
            const int tk = toklds[w][(t + 2 < Tt) ? t + 2 : Tt - 1];
            S.x = tabj[tk * 256];       S.y = tabj[tk * 256 + 64];
            S.z = tabj[tk * 256 + 128]; S.w = tabj[tk * 256 + 192];

            const float iv = fsig(gI);
            const float fv = fsig(gF);
            const float gv = ftanh(gG);
            const float ov = fsig(gO);
            c = fv * c + iv * gv;
            const float th = ftanh(c);
            hval = ov * th;
            if (t == myidx) { selh = hval; selc = c; }
            hsh[w][lane] = (__bf16)hval;
            barrier_novm();
        };

        for (int t = 0; t < Tt; t += 2) {
            step(t,     Sa);
            step(t + 1, Sb);
        }
    }

    // ---------------- epilogue MLP on the 4 gathered rows -------------------
    h2s[w][lane] = selh;
    __syncthreads();
#pragma unroll
    for (int p = 0; p < 2; ++p) {
        const int idx = tid + 256 * p;        // 512 (row, neuron) tasks
        const int rr = idx >> 7, n = idx & 127;
        float a = bl1[n];
        const float* wl = Wl1 + n * 64;
#pragma unroll 8
        for (int k = 0; k < 64; ++k) a += h2s[rr][k] * wl[k];
        ys[rr][n] = ftanh(a);
    }
    __syncthreads();
    if (tid < 16) {
        const int rr = tid >> 2, o = tid & 3;
        float a = bl2[o];
        const float* wl = Wl2 + o * 128;
#pragma unroll 8
        for (int k = 0; k < 128; ++k) a += ys[rr][k] * wl[k];
        out[(size_t)(b0 + rr) * 4 + o] = a;
    }
}

// ---------------------------------------------------------------------------
extern "C" void kernel_launch(void* const* d_in, const int* in_sizes, int n_in,
                              void* d_out, int out_size, void* d_ws, size_t ws_size,
                              hipStream_t stream) {
    const int*   s1   = (const int*)d_in[0];
    const int*   s2   = (const int*)d_in[1];
    const int*   l1   = (const int*)d_in[2];
    const int*   l2   = (const int*)d_in[3];
    // d_in[4], d_in[5] (s1_s, s2_s) unused by the reference
    const float* emb  = (const float*)d_in[6];
    const float* Wih1 = (const float*)d_in[7];
    const float* Whh1 = (const float*)d_in[8];
    const float* bih1 = (const float*)d_in[9];
    const float* bhh1 = (const float*)d_in[10];
    const float* Wih2 = (const float*)d_in[11];
    const float* Whh2 = (const float*)d_in[12];
    const float* bih2 = (const float*)d_in[13];
    const float* bhh2 = (const float*)d_in[14];
    const float* Wl1  = (const float*)d_in[15];
    const float* bl1  = (const float*)d_in[16];
    const float* Wl2  = (const float*)d_in[17];
    const float* bl2  = (const float*)d_in[18];
    float* out = (float*)d_out;

    float* tab1 = (float*)d_ws;                       // [V,256] fp32
    float* tab2 = tab1 + (size_t)Vv * 256;            // [V,256] fp32  (65.6 MB)

    dim3 grid((Vv + RR - 1) / RR, 2);
    build_tables<<<grid, 256, 0, stream>>>(emb, Wih1, bih1, bhh1,
                                           Wih2, bih2, bhh2, tab1, tab2);
    lstm_main<<<Bsz / 4, 256, 0, stream>>>(s1, s2, l1, l2, tab1, tab2,
                                           Whh1, Whh2, Wl1, bl1, Wl2, bl2, out);
}